// Round 4
// baseline (224.695 us; speedup 1.0000x reference)
//
#include <hip/hip_runtime.h>
#include <cstddef>

// Problem constants (from setup_inputs): B=16, J=1024, L=4096, D=512, fp32.
namespace {
constexpr int Bn = 16;
constexpr int Jn = 1024;
constexpr int Ln = 4096;
constexpr int Dn = 512;
constexpr int G  = 32;          // chunk length along J
constexpr int C  = Jn / G;      // 32 chunks
constexpr float kEps = 1e-4f;
constexpr int PASS1_BLOCKS = Bn * C;  // 512
}

__device__ __forceinline__ unsigned short bf16rne(float x) {
  unsigned u = __float_as_uint(x);
  unsigned r = (u + 0x7fffu + ((u >> 16) & 1u)) >> 16;   // round-to-nearest-even
  return (unsigned short)r;
}
__device__ __forceinline__ float bf16tof(unsigned short h) {
  return __uint_as_float(((unsigned)h) << 16);
}

// --- Kernel 1 (fused): blocks [0,512): per-(b,chunk) local EMA scan writing
// UNCORRECTED localh[b,j,d] (bf16), chunk-end E (fp32), A-prefix PA/Ap.
// Last-arriving block per batch b (via device-scope atomic on cnt[b]) runs the
// 32-step cross-chunk recurrence producing S[b,c,d] — removes a kernel launch.
// Blocks [512,528): per-batch boundary cumsum -> gather index idx[b,l].
__global__ __launch_bounds__(128) void k_fused1(
    const float* __restrict__ emb, const float* __restrict__ conf,
    const int* __restrict__ mask, const int* __restrict__ bnd,
    unsigned short* __restrict__ localh, float* __restrict__ E,
    float* __restrict__ PA, float* __restrict__ Ap, float* __restrict__ S,
    int* __restrict__ idx, int* __restrict__ cnt) {
  int blk = blockIdx.x;
  int t = threadIdx.x;                 // 0..127
  if (blk < PASS1_BLOCKS) {
    int b = blk / C, c = blk % C;
    int base = b * Jn + c * G;
    float4 s = make_float4(0.f, 0.f, 0.f, 0.f);
    float prod = 1.0f;
#pragma unroll 8
    for (int i = 0; i < G; ++i) {
      int j = base + i;
      float p = conf[j];
      p = fminf(fmaxf(p, kEps), 1.0f - kEps);
      bool m = (mask[j] != 0);
      float q = 1.0f - p;
      float4 e = ((const float4*)(emb + (size_t)j * Dn))[t];
      if (m) {
        s.x = p * e.x + q * s.x;
        s.y = p * e.y + q * s.y;
        s.z = p * e.z + q * s.z;
        s.w = p * e.w + q * s.w;
        prod *= q;
      }
      ushort4 h;
      h.x = bf16rne(s.x); h.y = bf16rne(s.y);
      h.z = bf16rne(s.z); h.w = bf16rne(s.w);
      ((ushort4*)(localh + (size_t)j * Dn))[t] = h;
      if (t == 0) PA[j] = prod;
    }
    ((float4*)(E + (size_t)blk * Dn))[t] = s;
    if (t == 0) Ap[blk] = prod;

    // last-arriver does the cross-chunk chain for batch b
    __threadfence();                   // make E/Ap visible device-wide
    __shared__ int who;
    if (t == 0) who = atomicAdd(&cnt[b], 1);
    __syncthreads();
    if (who == C - 1) {
      __threadfence();                 // acquire: see all other blocks' E/Ap
      float4 sv = make_float4(0.f, 0.f, 0.f, 0.f);
#pragma unroll 8
      for (int cc = 0; cc < C; ++cc) {
        ((float4*)(S + ((size_t)(b * C + cc)) * Dn))[t] = sv;
        float a = Ap[b * C + cc];
        float4 ev = ((const float4*)(E + ((size_t)(b * C + cc)) * Dn))[t];
        sv.x = ev.x + a * sv.x;
        sv.y = ev.y + a * sv.y;
        sv.z = ev.z + a * sv.z;
        sv.w = ev.w + a * sv.w;
      }
    }
  } else {
    int b = blk - PASS1_BLOCKS;
    const int per = Ln / 128;          // 32 elements per thread
    const int* row = bnd + (size_t)b * Ln;
    int s = 0;
#pragma unroll 8
    for (int i = 0; i < per; ++i) s += (row[t * per + i] != 0) ? 1 : 0;

    __shared__ int sh[128];
    sh[t] = s;
    __syncthreads();
    for (int off = 1; off < 128; off <<= 1) {
      int v = (t >= off) ? sh[t - off] : 0;
      __syncthreads();
      sh[t] += v;
      __syncthreads();
    }
    int run = sh[t] - s;               // exclusive prefix
#pragma unroll 8
    for (int i = 0; i < per; ++i) {
      run += (row[t * per + i] != 0) ? 1 : 0;
      int v = run - 1;
      v = v < 0 ? 0 : (v > Jn - 1 ? Jn - 1 : v);
      idx[(size_t)b * Ln + t * per + i] = v;
    }
  }
}

// --- Kernel 2: fused correction + gather upsample, XCD-swizzled.
// frames[b,l,:] = bf16(local[b,j,:]) + PA[b,j] * S[b, j/G, :],  j = idx[b,l].
__global__ __launch_bounds__(256) void k_gather(
    const unsigned short* __restrict__ localh, const float* __restrict__ PA,
    const float* __restrict__ S, const int* __restrict__ idx,
    float* __restrict__ out) {
  unsigned bid = blockIdx.x;                         // 0..32767
  unsigned sb = (bid & 7u) * 4096u + (bid >> 3);     // bijection on [0,32768)
  size_t tid = (size_t)sb * 256 + threadIdx.x;       // over B*L*(D/4)
  int d4 = (int)(tid & (Dn / 4 - 1));                // 0..127
  size_t bl = tid >> 7;                              // b*L + l
  int j = idx[bl];                                   // wave-uniform
  size_t b = bl >> 12;                               // L = 4096
  int c = j >> 5;                                    // chunk of j
  float pa = PA[b * Jn + (size_t)j];
  float4 sc = ((const float4*)(S + (b * C + (size_t)c) * Dn))[d4];
  ushort4 lh = ((const ushort4*)(localh + (b * Jn + (size_t)j) * Dn))[d4];
  float4 o;
  o.x = bf16tof(lh.x) + pa * sc.x;
  o.y = bf16tof(lh.y) + pa * sc.y;
  o.z = bf16tof(lh.z) + pa * sc.z;
  o.w = bf16tof(lh.w) + pa * sc.w;
  ((float4*)out)[tid] = o;
}

extern "C" void kernel_launch(void* const* d_in, const int* in_sizes, int n_in,
                              void* d_out, int out_size, void* d_ws, size_t ws_size,
                              hipStream_t stream) {
  const float* emb  = (const float*)d_in[0];   // B*J*D fp32
  const float* conf = (const float*)d_in[1];   // B*J fp32
  const int*   mask = (const int*)d_in[2];     // B*J bool -> int
  const int*   bnd  = (const int*)d_in[3];     // B*L bool -> int
  float* out = (float*)d_out;                  // B*L*D fp32

  float* ws = (float*)d_ws;
  unsigned short* localh = (unsigned short*)ws;          // B*J*D bf16 (16 MB)
  float* E   = ws + (size_t)Bn * Jn * Dn / 2;            // B*C*D fp32
  float* S   = E + (size_t)Bn * C * Dn;                  // B*C*D fp32
  float* PA  = S + (size_t)Bn * C * Dn;                  // B*J
  float* Ap  = PA + (size_t)Bn * Jn;                     // B*C
  int*   idx = (int*)(Ap + Bn * C);                      // B*L
  int*   cnt = idx + (size_t)Bn * Ln;                    // B  (last-arriver counters)

  hipMemsetAsync(cnt, 0, Bn * sizeof(int), stream);      // harness poisons ws
  hipLaunchKernelGGL(k_fused1, dim3(PASS1_BLOCKS + Bn), dim3(128), 0, stream,
                     emb, conf, mask, bnd, localh, E, PA, Ap, S, idx, cnt);
  size_t total4 = (size_t)Bn * Ln * (Dn / 4);
  hipLaunchKernelGGL(k_gather, dim3((unsigned)(total4 / 256)), dim3(256), 0, stream,
                     localh, PA, S, idx, out);
}

// Round 5
// 176.816 us; speedup vs baseline: 1.2708x; 1.2708x over previous
//
#include <hip/hip_runtime.h>
#include <cstddef>

// Problem constants (from setup_inputs): B=16, J=1024, L=4096, D=512, fp32.
namespace {
constexpr int Bn = 16;
constexpr int Jn = 1024;
constexpr int Ln = 4096;
constexpr int Dn = 512;
constexpr int G  = 32;          // chunk length along J
constexpr int C  = Jn / G;      // 32 chunks
constexpr float kEps = 1e-4f;
constexpr int PASS1_BLOCKS = Bn * C;  // 512
}

__device__ __forceinline__ unsigned short bf16rne(float x) {
  unsigned u = __float_as_uint(x);
  unsigned r = (u + 0x7fffu + ((u >> 16) & 1u)) >> 16;   // round-to-nearest-even
  return (unsigned short)r;
}
__device__ __forceinline__ float bf16tof(unsigned short h) {
  return __uint_as_float(((unsigned)h) << 16);
}

// --- Kernel 1 (fused): blocks [0,512): per-(b,chunk) local EMA scan writing
// UNCORRECTED localh[b,j,d] (bf16), chunk-end E (fp32), A-prefix PA/Ap.
// Blocks [512,528): per-batch boundary cumsum -> gather index idx[b,l].
// NOTE R4 lesson: do NOT fuse the cross-chunk recurrence here via
// __threadfence + atomic last-arriver — device-scope fence = per-block L2
// writeback, 512 of them cost ~60 us. Kernel-boundary coherence is cheaper.
__global__ __launch_bounds__(128) void k_fused1(
    const float* __restrict__ emb, const float* __restrict__ conf,
    const int* __restrict__ mask, const int* __restrict__ bnd,
    unsigned short* __restrict__ localh, float* __restrict__ E,
    float* __restrict__ PA, float* __restrict__ Ap, int* __restrict__ idx) {
  int blk = blockIdx.x;
  int t = threadIdx.x;                 // 0..127
  if (blk < PASS1_BLOCKS) {
    int b = blk / C, c = blk % C;
    int base = b * Jn + c * G;
    float4 s = make_float4(0.f, 0.f, 0.f, 0.f);
    float prod = 1.0f;
#pragma unroll 8
    for (int i = 0; i < G; ++i) {
      int j = base + i;
      float p = conf[j];
      p = fminf(fmaxf(p, kEps), 1.0f - kEps);
      bool m = (mask[j] != 0);
      float q = 1.0f - p;
      float4 e = ((const float4*)(emb + (size_t)j * Dn))[t];
      if (m) {
        s.x = p * e.x + q * s.x;
        s.y = p * e.y + q * s.y;
        s.z = p * e.z + q * s.z;
        s.w = p * e.w + q * s.w;
        prod *= q;
      }
      ushort4 h;
      h.x = bf16rne(s.x); h.y = bf16rne(s.y);
      h.z = bf16rne(s.z); h.w = bf16rne(s.w);
      ((ushort4*)(localh + (size_t)j * Dn))[t] = h;
      if (t == 0) PA[j] = prod;
    }
    ((float4*)(E + (size_t)blk * Dn))[t] = s;
    if (t == 0) Ap[blk] = prod;
  } else {
    int b = blk - PASS1_BLOCKS;
    const int per = Ln / 128;          // 32 elements per thread
    const int* row = bnd + (size_t)b * Ln;
    int s = 0;
#pragma unroll 8
    for (int i = 0; i < per; ++i) s += (row[t * per + i] != 0) ? 1 : 0;

    __shared__ int sh[128];
    sh[t] = s;
    __syncthreads();
    for (int off = 1; off < 128; off <<= 1) {
      int v = (t >= off) ? sh[t - off] : 0;
      __syncthreads();
      sh[t] += v;
      __syncthreads();
    }
    int run = sh[t] - s;               // exclusive prefix
#pragma unroll 8
    for (int i = 0; i < per; ++i) {
      run += (row[t * per + i] != 0) ? 1 : 0;
      int v = run - 1;
      v = v < 0 ? 0 : (v > Jn - 1 ? Jn - 1 : v);
      idx[(size_t)b * Ln + t * per + i] = v;
    }
  }
}

// --- Kernel 2: cross-chunk recurrence: S[b,c,d] = value entering chunk c.
__global__ __launch_bounds__(64) void k_chunk_start(
    const float* __restrict__ E, const float* __restrict__ Ap,
    float* __restrict__ S) {
  int tg = blockIdx.x * 64 + threadIdx.x;          // over B * D/4 = 2048
  int b = tg / (Dn / 4), d4 = tg % (Dn / 4);
  float4 s = make_float4(0.f, 0.f, 0.f, 0.f);
#pragma unroll 8
  for (int c = 0; c < C; ++c) {
    ((float4*)(S + ((size_t)(b * C + c)) * Dn))[d4] = s;
    float a = Ap[b * C + c];
    float4 e = ((const float4*)(E + ((size_t)(b * C + c)) * Dn))[d4];
    s.x = e.x + a * s.x;
    s.y = e.y + a * s.y;
    s.z = e.z + a * s.z;
    s.w = e.w + a * s.w;
  }
}

// --- Kernel 3: fused correction + gather upsample, XCD-swizzled.
// frames[b,l,:] = bf16(local[b,j,:]) + PA[b,j] * S[b, j/G, :],  j = idx[b,l].
__global__ __launch_bounds__(256) void k_gather(
    const unsigned short* __restrict__ localh, const float* __restrict__ PA,
    const float* __restrict__ S, const int* __restrict__ idx,
    float* __restrict__ out) {
  unsigned bid = blockIdx.x;                         // 0..32767
  unsigned sb = (bid & 7u) * 4096u + (bid >> 3);     // bijection on [0,32768)
  size_t tid = (size_t)sb * 256 + threadIdx.x;       // over B*L*(D/4)
  int d4 = (int)(tid & (Dn / 4 - 1));                // 0..127
  size_t bl = tid >> 7;                              // b*L + l
  int j = idx[bl];                                   // wave-uniform
  size_t b = bl >> 12;                               // L = 4096
  int c = j >> 5;                                    // chunk of j
  float pa = PA[b * Jn + (size_t)j];
  float4 sc = ((const float4*)(S + (b * C + (size_t)c) * Dn))[d4];
  ushort4 lh = ((const ushort4*)(localh + (b * Jn + (size_t)j) * Dn))[d4];
  float4 o;
  o.x = bf16tof(lh.x) + pa * sc.x;
  o.y = bf16tof(lh.y) + pa * sc.y;
  o.z = bf16tof(lh.z) + pa * sc.z;
  o.w = bf16tof(lh.w) + pa * sc.w;
  ((float4*)out)[tid] = o;
}

extern "C" void kernel_launch(void* const* d_in, const int* in_sizes, int n_in,
                              void* d_out, int out_size, void* d_ws, size_t ws_size,
                              hipStream_t stream) {
  const float* emb  = (const float*)d_in[0];   // B*J*D fp32
  const float* conf = (const float*)d_in[1];   // B*J fp32
  const int*   mask = (const int*)d_in[2];     // B*J bool -> int
  const int*   bnd  = (const int*)d_in[3];     // B*L bool -> int
  float* out = (float*)d_out;                  // B*L*D fp32

  float* ws = (float*)d_ws;
  unsigned short* localh = (unsigned short*)ws;          // B*J*D bf16 (16 MB)
  float* E   = ws + (size_t)Bn * Jn * Dn / 2;            // B*C*D fp32
  float* S   = E + (size_t)Bn * C * Dn;                  // B*C*D fp32
  float* PA  = S + (size_t)Bn * C * Dn;                  // B*J
  float* Ap  = PA + (size_t)Bn * Jn;                     // B*C
  int*   idx = (int*)(Ap + Bn * C);                      // B*L

  hipLaunchKernelGGL(k_fused1, dim3(PASS1_BLOCKS + Bn), dim3(128), 0, stream,
                     emb, conf, mask, bnd, localh, E, PA, Ap, idx);
  hipLaunchKernelGGL(k_chunk_start, dim3(Bn * (Dn / 4) / 64), dim3(64), 0, stream,
                     E, Ap, S);
  size_t total4 = (size_t)Bn * Ln * (Dn / 4);
  hipLaunchKernelGGL(k_gather, dim3((unsigned)(total4 / 256)), dim3(256), 0, stream,
                     localh, PA, S, idx, out);
}

// Round 7
// 174.052 us; speedup vs baseline: 1.2910x; 1.0159x over previous
//
#include <hip/hip_runtime.h>
#include <cstddef>

// Problem constants (from setup_inputs): B=16, J=1024, L=4096, D=512, fp32.
namespace {
constexpr int Bn = 16;
constexpr int Jn = 1024;
constexpr int Ln = 4096;
constexpr int Dn = 512;
constexpr int G  = 16;          // chunk length along J (R6: 32->16 for occupancy)
constexpr int C  = Jn / G;      // 64 chunks
constexpr float kEps = 1e-4f;
constexpr int PASS1_BLOCKS = Bn * C;  // 1024
}

// clang native vector type — required by __builtin_nontemporal_* (HIP's float4
// is a wrapper class the builtin rejects). Same 16-byte layout.
typedef float fvec4 __attribute__((ext_vector_type(4)));

__device__ __forceinline__ unsigned short bf16rne(float x) {
  unsigned u = __float_as_uint(x);
  unsigned r = (u + 0x7fffu + ((u >> 16) & 1u)) >> 16;   // round-to-nearest-even
  return (unsigned short)r;
}
__device__ __forceinline__ float bf16tof(unsigned short h) {
  return __uint_as_float(((unsigned)h) << 16);
}

// --- Kernel 1 (fused): blocks [0,1024): per-(b,chunk) local EMA scan writing
// UNCORRECTED localh[b,j,d] (bf16), chunk-end E (fp32), A-prefix PA/Ap.
// XCD affinity: round-robin dispatch puts raw block bid on XCD bid&7; we remap
// so batch b's blocks run on XCD b/2 — the same XCD whose L2 the gather kernel
// (swizzled the same way) will read localh[b] from. L2 is write-back and
// persists across launches.
// Blocks [1024,1040): per-batch boundary cumsum -> gather index idx[b,l].
// R4 lesson: no device-fence last-arriver fusion (512 L2 writebacks ~ 60us).
__global__ __launch_bounds__(128) void k_fused1(
    const float* __restrict__ emb, const float* __restrict__ conf,
    const int* __restrict__ mask, const int* __restrict__ bnd,
    unsigned short* __restrict__ localh, float* __restrict__ E,
    float* __restrict__ PA, float* __restrict__ Ap, int* __restrict__ idx) {
  int blk = blockIdx.x;
  int t = threadIdx.x;                 // 0..127
  if (blk < PASS1_BLOCKS) {
    int xcd  = blk & 7;
    int slot = blk >> 3;               // 0..127
    int b = 2 * xcd + (slot & 1);      // batches 2x,2x+1 on XCD x
    int c = slot >> 1;                 // 0..63
    int base = b * Jn + c * G;
    fvec4 s = (fvec4)(0.f);
    float prod = 1.0f;
#pragma unroll 8
    for (int i = 0; i < G; ++i) {
      int j = base + i;
      float p = conf[j];
      p = fminf(fmaxf(p, kEps), 1.0f - kEps);
      bool m = (mask[j] != 0);
      float q = 1.0f - p;
      fvec4 e = __builtin_nontemporal_load(((const fvec4*)(emb + (size_t)j * Dn)) + t);
      if (m) {
        s = p * e + q * s;
        prod *= q;
      }
      ushort4 h;
      h.x = bf16rne(s.x); h.y = bf16rne(s.y);
      h.z = bf16rne(s.z); h.w = bf16rne(s.w);
      ((ushort4*)(localh + (size_t)j * Dn))[t] = h;   // keep in L2 (re-read by gather)
      if (t == 0) PA[j] = prod;
    }
    ((fvec4*)(E + ((size_t)(b * C + c)) * Dn))[t] = s;
    if (t == 0) Ap[b * C + c] = prod;
  } else {
    int b = blk - PASS1_BLOCKS;
    const int per = Ln / 128;          // 32 elements per thread
    const int* row = bnd + (size_t)b * Ln;
    int s = 0;
#pragma unroll 8
    for (int i = 0; i < per; ++i) s += (row[t * per + i] != 0) ? 1 : 0;

    __shared__ int sh[128];
    sh[t] = s;
    __syncthreads();
    for (int off = 1; off < 128; off <<= 1) {
      int v = (t >= off) ? sh[t - off] : 0;
      __syncthreads();
      sh[t] += v;
      __syncthreads();
    }
    int run = sh[t] - s;               // exclusive prefix
#pragma unroll 8
    for (int i = 0; i < per; ++i) {
      run += (row[t * per + i] != 0) ? 1 : 0;
      int v = run - 1;
      v = v < 0 ? 0 : (v > Jn - 1 ? Jn - 1 : v);
      idx[(size_t)b * Ln + t * per + i] = v;
    }
  }
}

// --- Kernel 2: cross-chunk recurrence: S[b,c,d] = value entering chunk c.
__global__ __launch_bounds__(64) void k_chunk_start(
    const float* __restrict__ E, const float* __restrict__ Ap,
    float* __restrict__ S) {
  int tg = blockIdx.x * 64 + threadIdx.x;          // over B * D/4 = 2048
  int b = tg / (Dn / 4), d4 = tg % (Dn / 4);
  fvec4 s = (fvec4)(0.f);
#pragma unroll 8
  for (int c = 0; c < C; ++c) {
    ((fvec4*)(S + ((size_t)(b * C + c)) * Dn))[d4] = s;
    float a = Ap[b * C + c];
    fvec4 e = ((const fvec4*)(E + ((size_t)(b * C + c)) * Dn))[d4];
    s = e + a * s;
  }
}

// --- Kernel 3: fused correction + gather upsample, XCD-swizzled.
// frames[b,l,:] = bf16(local[b,j,:]) + PA[b,j] * S[b, j/G, :],  j = idx[b,l].
// Swizzle gives XCD x the contiguous span = batches {2x,2x+1}, matching
// k_fused1's affinity so localh reads hit the local L2. Out stores are
// nontemporal: write-once 134 MB must not evict localh/S from L2.
__global__ __launch_bounds__(256) void k_gather(
    const unsigned short* __restrict__ localh, const float* __restrict__ PA,
    const float* __restrict__ S, const int* __restrict__ idx,
    float* __restrict__ out) {
  unsigned bid = blockIdx.x;                         // 0..32767
  unsigned sb = (bid & 7u) * 4096u + (bid >> 3);     // bijection on [0,32768)
  size_t tid = (size_t)sb * 256 + threadIdx.x;       // over B*L*(D/4)
  int d4 = (int)(tid & (Dn / 4 - 1));                // 0..127
  size_t bl = tid >> 7;                              // b*L + l
  int j = idx[bl];                                   // wave-uniform
  size_t b = bl >> 12;                               // L = 4096
  int c = j >> 4;                                    // chunk of j (G=16)
  float pa = PA[b * Jn + (size_t)j];
  fvec4 sc = ((const fvec4*)(S + (b * C + (size_t)c) * Dn))[d4];
  ushort4 lh = ((const ushort4*)(localh + (b * Jn + (size_t)j) * Dn))[d4];
  fvec4 o;
  o.x = bf16tof(lh.x) + pa * sc.x;
  o.y = bf16tof(lh.y) + pa * sc.y;
  o.z = bf16tof(lh.z) + pa * sc.z;
  o.w = bf16tof(lh.w) + pa * sc.w;
  __builtin_nontemporal_store(o, ((fvec4*)out) + tid);
}

extern "C" void kernel_launch(void* const* d_in, const int* in_sizes, int n_in,
                              void* d_out, int out_size, void* d_ws, size_t ws_size,
                              hipStream_t stream) {
  const float* emb  = (const float*)d_in[0];   // B*J*D fp32
  const float* conf = (const float*)d_in[1];   // B*J fp32
  const int*   mask = (const int*)d_in[2];     // B*J bool -> int
  const int*   bnd  = (const int*)d_in[3];     // B*L bool -> int
  float* out = (float*)d_out;                  // B*L*D fp32

  float* ws = (float*)d_ws;
  unsigned short* localh = (unsigned short*)ws;          // B*J*D bf16 (16.8 MB)
  float* E   = ws + (size_t)Bn * Jn * Dn / 2;            // B*C*D fp32 (2 MB)
  float* S   = E + (size_t)Bn * C * Dn;                  // B*C*D fp32 (2 MB)
  float* PA  = S + (size_t)Bn * C * Dn;                  // B*J
  float* Ap  = PA + (size_t)Bn * Jn;                     // B*C
  int*   idx = (int*)(Ap + Bn * C);                      // B*L

  hipLaunchKernelGGL(k_fused1, dim3(PASS1_BLOCKS + Bn), dim3(128), 0, stream,
                     emb, conf, mask, bnd, localh, E, PA, Ap, idx);
  hipLaunchKernelGGL(k_chunk_start, dim3(Bn * (Dn / 4) / 64), dim3(64), 0, stream,
                     E, Ap, S);
  size_t total4 = (size_t)Bn * Ln * (Dn / 4);
  hipLaunchKernelGGL(k_gather, dim3((unsigned)(total4 / 256)), dim3(256), 0, stream,
                     localh, PA, S, idx, out);
}